// Round 3
// baseline (352.773 us; speedup 1.0000x reference)
//
#include <hip/hip_runtime.h>
#include <hip/hip_bf16.h>
#include <stdint.h>

// Problem constants (B,T,D,NH from reference)
#define NHh 16
#define Dm  1024
#define HD  64          // head dim = D/NH
#define Bb  4
#define Tt  4096
#define NCH 64          // chunks along T for the two-pass scans
#define CHL 64          // chunk length (NCH*CHL == Tt)

using bf16 = __hip_bfloat16;
typedef __attribute__((ext_vector_type(8))) short short8;   // 8 bf16 in 4 VGPRs (MFMA A/B frag)
typedef __attribute__((ext_vector_type(4))) float f32x4;    // MFMA C/D frag

__device__ __forceinline__ float bf2f(bf16 v) { return __bfloat162float(v); }

// fp32 -> bf16 cast, vectorized; n divisible by 4
__global__ void cast_f32_to_bf16(const float* __restrict__ in, bf16* __restrict__ out, int n) {
  const int stride = gridDim.x * blockDim.x;
  for (int i = blockIdx.x * blockDim.x + threadIdx.x; i * 4 < n; i += stride) {
    const float4 v = *(const float4*)(in + (size_t)i * 4);
    ushort4 o;
    o.x = __bfloat16_as_ushort(__float2bfloat16(v.x));
    o.y = __bfloat16_as_ushort(__float2bfloat16(v.y));
    o.z = __bfloat16_as_ushort(__float2bfloat16(v.z));
    o.w = __bfloat16_as_ushort(__float2bfloat16(v.w));
    *(ushort4*)(out + (size_t)i * 4) = o;
  }
}

// C[m][n] = sum_k A[m][k] * W[n][k]  (both K-contiguous row-major, bf16)
// 128x128 tile, 256 threads (4 waves in 2x2, each 64x64 = 4x4 MFMA 16x16x32).
template <bool OUT_BF16>
__global__ __launch_bounds__(256) void gemm_bt(const bf16* __restrict__ A,
                                               const bf16* __restrict__ W,
                                               void* __restrict__ Cout,
                                               int M, int N, int K) {
  __shared__ __align__(16) unsigned short sA[128][32];   // 8 KB
  __shared__ __align__(16) unsigned short sB[128][32];   // 8 KB
  const int tid  = threadIdx.x;
  const int lane = tid & 63;
  const int wave = tid >> 6;
  const int bn = blockIdx.x * 128;
  const int bm = blockIdx.y * 128;
  const int wm = (wave & 1) * 64;
  const int wn = (wave >> 1) * 64;
  const int quad = lane >> 4;
  const int l16  = lane & 15;

  f32x4 acc[4][4] = {};

  // staging map: thread tid covers rows (tid>>2) and (tid>>2)+64, 8 bf16 at col (tid&3)*8
  const int rowL = tid >> 2;          // 0..63
  const int col8 = (tid & 3) * 8;     // 0,8,16,24

  for (int k0 = 0; k0 < K; k0 += 32) {
    const uint4 a0 = *(const uint4*)(A + (size_t)(bm + rowL) * K + (k0 + col8));
    const uint4 a1 = *(const uint4*)(A + (size_t)(bm + 64 + rowL) * K + (k0 + col8));
    const uint4 b0 = *(const uint4*)(W + (size_t)(bn + rowL) * K + (k0 + col8));
    const uint4 b1 = *(const uint4*)(W + (size_t)(bn + 64 + rowL) * K + (k0 + col8));
    *(uint4*)&sA[rowL][col8]      = a0;
    *(uint4*)&sA[64 + rowL][col8] = a1;
    *(uint4*)&sB[rowL][col8]      = b0;
    *(uint4*)&sB[64 + rowL][col8] = b1;
    __syncthreads();

    short8 af[4], bfv[4];
#pragma unroll
    for (int i = 0; i < 4; i++) af[i]  = *(const short8*)&sA[wm + i * 16 + l16][quad * 8];
#pragma unroll
    for (int j = 0; j < 4; j++) bfv[j] = *(const short8*)&sB[wn + j * 16 + l16][quad * 8];
#pragma unroll
    for (int i = 0; i < 4; i++)
#pragma unroll
      for (int j = 0; j < 4; j++)
        acc[i][j] = __builtin_amdgcn_mfma_f32_16x16x32_bf16(af[i], bfv[j], acc[i][j], 0, 0, 0);
    __syncthreads();
  }

  // C/D layout (HW-verified): col = lane&15, row = (lane>>4)*4 + reg
#pragma unroll
  for (int i = 0; i < 4; i++) {
#pragma unroll
    for (int j = 0; j < 4; j++) {
      const int col = bn + wn + j * 16 + l16;
#pragma unroll
      for (int r = 0; r < 4; r++) {
        const int row = bm + wm + i * 16 + quad * 4 + r;
        if constexpr (OUT_BF16)
          ((bf16*)Cout)[(size_t)row * N + col] = __float2bfloat16(acc[i][j][r]);
        else
          ((float*)Cout)[(size_t)row * N + col] = acc[i][j][r];
      }
    }
  }
}

// penalty[b,t] = (phi[b,t] - cumsum(phi)[b,t]/(t+1))^2 ; block-scan per batch
__global__ void phi_penalty_kernel(const float* __restrict__ phi, float* __restrict__ penalty) {
  const int b = blockIdx.x;
  const int tid = threadIdx.x;            // 256
  const int lane = tid & 63, wid = tid >> 6;
  __shared__ float wsum[4];
  __shared__ float carry_s;
  if (tid == 0) carry_s = 0.f;
  __syncthreads();
  for (int r = 0; r < Tt / 256; r++) {
    const int t = r * 256 + tid;
    const float v = phi[b * Tt + t];
    float incl = v;
#pragma unroll
    for (int off = 1; off < 64; off <<= 1) {
      float n = __shfl_up(incl, off, 64);
      if (lane >= off) incl += n;
    }
    if (lane == 63) wsum[wid] = incl;
    __syncthreads();
    float woff = carry_s;
    for (int wpre = 0; wpre < wid; wpre++) woff += wsum[wpre];
    const float csum = woff + incl;
    const float mean = csum / (float)(t + 1);
    const float dphi = v - mean;
    penalty[b * Tt + t] = dphi * dphi;
    __syncthreads();
    if (tid == 0) carry_s += wsum[0] + wsum[1] + wsum[2] + wsum[3];
    __syncthreads();
  }
}

// chunk sums of w_sq: S[b,h,c,d]
__global__ void scan_sq_phase1(const bf16* __restrict__ w, float* __restrict__ S) {
  const int c = blockIdx.x, h = blockIdx.y, b = blockIdx.z, d = threadIdx.x;
  const bf16* wp = w + ((size_t)(b * Tt + c * CHL)) * Dm + h * HD + d;
  float acc = 0.f;
#pragma unroll 4
  for (int i = 0; i < CHL; i++) { const float v = bf2f(wp[(size_t)i * Dm]); acc += v * v; }
  S[(((size_t)(b * NHh + h) * NCH) + c) * HD + d] = acc;
}

// in-place exclusive prefix over chunks, per (b,h,d)
__global__ void prefix_vec(float* __restrict__ S) {
  const int bh = blockIdx.x, d = threadIdx.x;
  float* p = S + (size_t)bh * NCH * HD + d;
  float run = 0.f;
  for (int c = 0; c < NCH; c++) { const float v = p[(size_t)c * HD]; p[(size_t)c * HD] = run; run += v; }
}

__global__ void prefix_scalar(float* __restrict__ SA) {
  const int bh = threadIdx.x;   // 64 threads, 1 block (Bb*NHh == 64)
  float* p = SA + (size_t)bh * NCH;
  float run = 0.f;
  for (int c = 0; c < NCH; c++) { const float v = p[c]; p[c] = run; run += v; }
}

// tssa[b,h,t] = temp[h] * sum_d( w_sq / max(cumsum_t(w_sq),1e-12) )
__global__ void tssa_phase3(const bf16* __restrict__ w, const float* __restrict__ Sex,
                            const float* __restrict__ temp, float* __restrict__ tssa) {
  const int c = blockIdx.x, h = blockIdx.y, b = blockIdx.z, d = threadIdx.x;
  float acc = Sex[(((size_t)(b * NHh + h) * NCH) + c) * HD + d];
  const bf16* wp = w + ((size_t)(b * Tt + c * CHL)) * Dm + h * HD + d;
  const float tv = temp[h];
  float* op = tssa + (size_t)(b * NHh + h) * Tt + c * CHL;
  for (int i = 0; i < CHL; i++) {
    const float v = bf2f(wp[(size_t)i * Dm]);
    const float sq = v * v;
    acc += sq;
    float val = sq / fmaxf(acc, 1e-12f);
#pragma unroll
    for (int off = 32; off > 0; off >>= 1) val += __shfl_xor(val, off, 64);
    if (d == 0) op[i] = tv * val;
  }
}

// softmax over heads; writes fp32 alpha straight into d_out's alpha region
__global__ void softmax_heads(const float* __restrict__ tssa, const float* __restrict__ penalty,
                              const float* __restrict__ gamma, float* __restrict__ alpha_f) {
  const int idx = blockIdx.x * blockDim.x + threadIdx.x;  // over B*T
  const int b = idx >> 12;     // T = 4096
  const int t = idx & 4095;
  const float pen = penalty[idx];
  float sc[NHh];
  float mx = -1e30f;
#pragma unroll
  for (int h = 0; h < NHh; h++) {
    const float s = tssa[((size_t)(b * NHh + h)) * Tt + t] - gamma[h] * pen;
    sc[h] = s;
    mx = fmaxf(mx, s);
  }
  float sum = 0.f;
#pragma unroll
  for (int h = 0; h < NHh; h++) { const float e = expf(sc[h] - mx); sc[h] = e; sum += e; }
  const float inv = 1.f / sum;
#pragma unroll
  for (int h = 0; h < NHh; h++) {
    alpha_f[((size_t)(b * NHh + h)) * Tt + t] = sc[h] * inv;
  }
}

// chunk sums of w_sq*alpha (vec) and alpha (scalar)
__global__ void dots_phase1(const bf16* __restrict__ w, const float* __restrict__ alpha_f,
                            float* __restrict__ S2, float* __restrict__ SA) {
  const int c = blockIdx.x, h = blockIdx.y, b = blockIdx.z, d = threadIdx.x;
  const bf16* wp = w + ((size_t)(b * Tt + c * CHL)) * Dm + h * HD + d;
  const float* ap = alpha_f + (size_t)(b * NHh + h) * Tt + c * CHL;
  float acc = 0.f, acca = 0.f;
  for (int i = 0; i < CHL; i++) {
    const float a = ap[i];
    const float v = bf2f(wp[(size_t)i * Dm]);
    acc += v * v * a;
    acca += a;
  }
  S2[(((size_t)(b * NHh + h) * NCH) + c) * HD + d] = acc;
  if (d == 0) SA[(size_t)(b * NHh + h) * NCH + c] = acca;
}

// y'[b,t,h*64+d] = -w * alpha * min(1/(1+dots), 1e4), bf16
__global__ void y_phase3(const bf16* __restrict__ w, const float* __restrict__ alpha_f,
                         const float* __restrict__ S2ex, const float* __restrict__ SAex,
                         bf16* __restrict__ yprime) {
  const int c = blockIdx.x, h = blockIdx.y, b = blockIdx.z, d = threadIdx.x;
  float accd = S2ex[(((size_t)(b * NHh + h) * NCH) + c) * HD + d];
  float acca = SAex[(size_t)(b * NHh + h) * NCH + c];
  const bf16* wp = w + ((size_t)(b * Tt + c * CHL)) * Dm + h * HD + d;
  const float* ap = alpha_f + (size_t)(b * NHh + h) * Tt + c * CHL;
  bf16* yp = yprime + ((size_t)(b * Tt + c * CHL)) * Dm + h * HD + d;
  for (int i = 0; i < CHL; i++) {
    const float a = ap[i];
    const float v = bf2f(wp[(size_t)i * Dm]);
    const float sq = v * v;
    accd += sq * a;
    acca += a;
    const float dots = accd / (acca + 1e-8f);
    const float attn = fminf(1.f / (1.f + dots), 10000.f);
    yp[(size_t)i * Dm] = __float2bfloat16(-v * a * attn);
  }
}

extern "C" void kernel_launch(void* const* d_in, const int* in_sizes, int n_in,
                              void* d_out, int out_size, void* d_ws, size_t ws_size,
                              hipStream_t stream) {
  // Reference dtypes: ALL inputs float32, outputs (y, alpha) float32.
  const float* x     = (const float*)d_in[0];
  const float* phi   = (const float*)d_in[1];
  const float* Wattn = (const float*)d_in[2];
  const float* Wproj = (const float*)d_in[3];
  const float* gamma = (const float*)d_in[4];
  const float* temp  = (const float*)d_in[5];

  float* y_out    = (float*)d_out;                          // (B,T,D) fp32
  float* alpha_f  = y_out + (size_t)Bb * Tt * Dm;           // (B,NH,T) fp32

  char* ws = (char*)d_ws;
  bf16*  x_bf   = (bf16*)ws;  ws += (size_t)Bb * Tt * Dm * 2;         // 32 MB
  bf16*  Wa_bf  = (bf16*)ws;  ws += (size_t)Dm * Dm * 2;              // 2 MB
  bf16*  Wp_bf  = (bf16*)ws;  ws += (size_t)Dm * Dm * 2;              // 2 MB
  bf16*  w_bf   = (bf16*)ws;  ws += (size_t)Bb * Tt * Dm * 2;         // 32 MB
  float* tssa   = (float*)ws; ws += (size_t)Bb * NHh * Tt * 4;        // 1 MB
  float* pen    = (float*)ws; ws += (size_t)Bb * Tt * 4;              // 64 KB
  float* S1     = (float*)ws; ws += (size_t)Bb * NHh * NCH * HD * 4;  // 1 MB
  float* S2     = (float*)ws; ws += (size_t)Bb * NHh * NCH * HD * 4;  // 1 MB
  float* SA     = (float*)ws; ws += (size_t)Bb * NHh * NCH * 4;       // 16 KB
  bf16*  yprime = x_bf;  // alias: x_bf is dead after GEMM1

  const int M = Bb * Tt, N = Dm, K = Dm;
  dim3 gg(N / 128, M / 128), gb(256);
  dim3 g3(NCH, NHh, Bb), b64(64);

  cast_f32_to_bf16<<<dim3(1024), dim3(256), 0, stream>>>(x, x_bf, Bb * Tt * Dm);
  cast_f32_to_bf16<<<dim3(256), dim3(256), 0, stream>>>(Wattn, Wa_bf, Dm * Dm);
  cast_f32_to_bf16<<<dim3(256), dim3(256), 0, stream>>>(Wproj, Wp_bf, Dm * Dm);

  gemm_bt<true><<<gg, gb, 0, stream>>>(x_bf, Wa_bf, (void*)w_bf, M, N, K);
  phi_penalty_kernel<<<dim3(Bb), dim3(256), 0, stream>>>(phi, pen);
  scan_sq_phase1<<<g3, b64, 0, stream>>>(w_bf, S1);
  prefix_vec<<<dim3(Bb * NHh), b64, 0, stream>>>(S1);
  tssa_phase3<<<g3, b64, 0, stream>>>(w_bf, S1, temp, tssa);
  softmax_heads<<<dim3(Bb * Tt / 256), dim3(256), 0, stream>>>(tssa, pen, gamma, alpha_f);
  dots_phase1<<<g3, b64, 0, stream>>>(w_bf, alpha_f, S2, SA);
  prefix_vec<<<dim3(Bb * NHh), b64, 0, stream>>>(S2);
  prefix_scalar<<<dim3(1), b64, 0, stream>>>(SA);
  y_phase3<<<g3, b64, 0, stream>>>(w_bf, alpha_f, S2, SA, yprime);
  gemm_bt<false><<<gg, gb, 0, stream>>>(yprime, Wp_bf, (void*)y_out, M, N, K);
}

// Round 4
// 337.004 us; speedup vs baseline: 1.0468x; 1.0468x over previous
//
#include <hip/hip_runtime.h>
#include <hip/hip_bf16.h>
#include <stdint.h>

// Problem constants (B,T,D,NH from reference)
#define NHh 16
#define Dm  1024
#define HD  64          // head dim = D/NH
#define Bb  4
#define Tt  4096
#define NCH 64          // chunks along T for the two-pass scans
#define CHL 64          // chunk length (NCH*CHL == Tt)

using bf16 = __hip_bfloat16;
typedef __attribute__((ext_vector_type(8))) short short8;   // 8 bf16 in 4 VGPRs (MFMA A/B frag)
typedef __attribute__((ext_vector_type(4))) float f32x4;    // MFMA C/D frag

__device__ __forceinline__ float bf2f(bf16 v) { return __bfloat162float(v); }

// async global->LDS, 16B per lane. LDS dest is wave-uniform base + lane*16.
__device__ __forceinline__ void gld_lds16(const void* g, void* l) {
  __builtin_amdgcn_global_load_lds(
      (const __attribute__((address_space(1))) unsigned int*)g,
      (__attribute__((address_space(3))) unsigned int*)l, 16, 0, 0);
}

// fp32 -> bf16 cast, vectorized; n divisible by 4
__global__ void cast_f32_to_bf16(const float* __restrict__ in, bf16* __restrict__ out, int n) {
  const int stride = gridDim.x * blockDim.x;
  for (int i = blockIdx.x * blockDim.x + threadIdx.x; i * 4 < n; i += stride) {
    const float4 v = *(const float4*)(in + (size_t)i * 4);
    ushort4 o;
    o.x = __bfloat16_as_ushort(__float2bfloat16(v.x));
    o.y = __bfloat16_as_ushort(__float2bfloat16(v.y));
    o.z = __bfloat16_as_ushort(__float2bfloat16(v.z));
    o.w = __bfloat16_as_ushort(__float2bfloat16(v.w));
    *(ushort4*)(out + (size_t)i * 4) = o;
  }
}

// C[m][n] = sum_k A[m][k] * W[n][k]  (both K-contiguous row-major, bf16)
// 128x128 tile, 256 threads (4 waves in 2x2, each 64x64 = 4x4 MFMA 16x16x32).
// Staging via global_load_lds width=16 (m97 pattern): LDS addr of tid = tid*16B
// == &sA[tid>>2][(tid&3)*8]; per wave-issue base = sA + wave*1024B, lane adds lane*16B.
// WRITE_S1: fuse chunk sums of bf16(w)^2 into the epilogue (each block holds
// complete 64-row chunks x its 128 cols -> no atomics).
template <bool OUT_BF16, bool WRITE_S1>
__global__ __launch_bounds__(256) void gemm_bt(const bf16* __restrict__ A,
                                               const bf16* __restrict__ W,
                                               void* __restrict__ Cout,
                                               float* __restrict__ S1,
                                               int M, int N, int K) {
  __shared__ __align__(16) unsigned short sA[128][32];   // 8 KB
  __shared__ __align__(16) unsigned short sB[128][32];   // 8 KB
  const int tid  = threadIdx.x;
  const int lane = tid & 63;
  const int wave = tid >> 6;
  const int bn = blockIdx.x * 128;
  const int bm = blockIdx.y * 128;
  const int wm = (wave & 1) * 64;
  const int wn = (wave >> 1) * 64;
  const int quad = lane >> 4;
  const int l16  = lane & 15;

  f32x4 acc[4][4] = {};

  // staging map: thread tid covers rows (tid>>2) and (tid>>2)+64, 8 bf16 at col (tid&3)*8
  const int rowL = tid >> 2;          // 0..63
  const int col8 = (tid & 3) * 8;     // 0,8,16,24

  for (int k0 = 0; k0 < K; k0 += 32) {
    const bf16* g0 = A + (size_t)(bm + rowL) * K + (k0 + col8);
    const bf16* g1 = A + (size_t)(bm + 64 + rowL) * K + (k0 + col8);
    gld_lds16(g0, (unsigned short*)sA + wave * 512);
    gld_lds16(g1, (unsigned short*)sA + 2048 + wave * 512);
    const bf16* h0 = W + (size_t)(bn + rowL) * K + (k0 + col8);
    const bf16* h1 = W + (size_t)(bn + 64 + rowL) * K + (k0 + col8);
    gld_lds16(h0, (unsigned short*)sB + wave * 512);
    gld_lds16(h1, (unsigned short*)sB + 2048 + wave * 512);
    __syncthreads();

    short8 af[4], bfv[4];
#pragma unroll
    for (int i = 0; i < 4; i++) af[i]  = *(const short8*)&sA[wm + i * 16 + l16][quad * 8];
#pragma unroll
    for (int j = 0; j < 4; j++) bfv[j] = *(const short8*)&sB[wn + j * 16 + l16][quad * 8];
#pragma unroll
    for (int i = 0; i < 4; i++)
#pragma unroll
      for (int j = 0; j < 4; j++)
        acc[i][j] = __builtin_amdgcn_mfma_f32_16x16x32_bf16(af[i], bfv[j], acc[i][j], 0, 0, 0);
    __syncthreads();
  }

  // C/D layout (HW-verified): col = lane&15, row = (lane>>4)*4 + reg
#pragma unroll
  for (int j = 0; j < 4; j++) {
    const int col = bn + wn + j * 16 + l16;
    float ssum = 0.f;
#pragma unroll
    for (int i = 0; i < 4; i++) {
#pragma unroll
      for (int r = 0; r < 4; r++) {
        const int row = bm + wm + i * 16 + quad * 4 + r;
        if constexpr (OUT_BF16) {
          const bf16 hv = __float2bfloat16(acc[i][j][r]);
          ((bf16*)Cout)[(size_t)row * N + col] = hv;
          if constexpr (WRITE_S1) { const float fv = bf2f(hv); ssum += fv * fv; }
        } else {
          ((float*)Cout)[(size_t)row * N + col] = acc[i][j][r];
        }
      }
    }
    if constexpr (WRITE_S1) {
      // reduce over the 4 quads (same l16 -> same col); rows union = full 64-chunk
      ssum += __shfl_xor(ssum, 16, 64);
      ssum += __shfl_xor(ssum, 32, 64);
      if (quad == 0) {
        const int r0 = bm + wm;           // first row of this wave's chunk
        const int b  = r0 >> 12;          // / Tt
        const int c  = (r0 & (Tt - 1)) >> 6;
        const int h  = col >> 6, d = col & 63;
        S1[(((size_t)(b * NHh + h) * NCH) + c) * HD + d] = ssum;
      }
    }
  }
}

// penalty[b,t] = (phi[b,t] - cumsum(phi)[b,t]/(t+1))^2 ; block-scan per batch
__global__ void phi_penalty_kernel(const float* __restrict__ phi, float* __restrict__ penalty) {
  const int b = blockIdx.x;
  const int tid = threadIdx.x;            // 256
  const int lane = tid & 63, wid = tid >> 6;
  __shared__ float wsum[4];
  __shared__ float carry_s;
  if (tid == 0) carry_s = 0.f;
  __syncthreads();
  for (int r = 0; r < Tt / 256; r++) {
    const int t = r * 256 + tid;
    const float v = phi[b * Tt + t];
    float incl = v;
#pragma unroll
    for (int off = 1; off < 64; off <<= 1) {
      float n = __shfl_up(incl, off, 64);
      if (lane >= off) incl += n;
    }
    if (lane == 63) wsum[wid] = incl;
    __syncthreads();
    float woff = carry_s;
    for (int wpre = 0; wpre < wid; wpre++) woff += wsum[wpre];
    const float csum = woff + incl;
    const float mean = csum / (float)(t + 1);
    const float dphi = v - mean;
    penalty[b * Tt + t] = dphi * dphi;
    __syncthreads();
    if (tid == 0) carry_s += wsum[0] + wsum[1] + wsum[2] + wsum[3];
    __syncthreads();
  }
}

// in-place exclusive prefix over chunks, per (b,h,d)
__global__ void prefix_vec(float* __restrict__ S) {
  const int bh = blockIdx.x, d = threadIdx.x;
  float* p = S + (size_t)bh * NCH * HD + d;
  float run = 0.f;
  for (int c = 0; c < NCH; c++) { const float v = p[(size_t)c * HD]; p[(size_t)c * HD] = run; run += v; }
}

// fused exclusive prefix for dots: S2 (vec, serial per d) + SA (scalar, wave scan)
__global__ void prefix_dots(float* __restrict__ S2, float* __restrict__ SA) {
  const int bh = blockIdx.x, d = threadIdx.x;   // 64 threads
  // SA: lane d holds chunk d's sum; inclusive wave scan -> exclusive
  const float v = SA[(size_t)bh * NCH + d];
  float incl = v;
#pragma unroll
  for (int off = 1; off < 64; off <<= 1) {
    const float n = __shfl_up(incl, off, 64);
    if (d >= off) incl += n;
  }
  SA[(size_t)bh * NCH + d] = incl - v;
  // S2 column scan
  float* p = S2 + (size_t)bh * NCH * HD + d;
  float run = 0.f;
  for (int c = 0; c < NCH; c++) { const float w = p[(size_t)c * HD]; p[(size_t)c * HD] = run; run += w; }
}

// tssa[b,h,t] = temp[h] * sum_d( w_sq / max(cumsum_t(w_sq),1e-12) )
__global__ void tssa_phase3(const bf16* __restrict__ w, const float* __restrict__ Sex,
                            const float* __restrict__ temp, float* __restrict__ tssa) {
  const int c = blockIdx.x, h = blockIdx.y, b = blockIdx.z, d = threadIdx.x;
  float acc = Sex[(((size_t)(b * NHh + h) * NCH) + c) * HD + d];
  const bf16* wp = w + ((size_t)(b * Tt + c * CHL)) * Dm + h * HD + d;
  const float tv = temp[h];
  float* op = tssa + (size_t)(b * NHh + h) * Tt + c * CHL;
  for (int i = 0; i < CHL; i++) {
    const float v = bf2f(wp[(size_t)i * Dm]);
    const float sq = v * v;
    acc += sq;
    float val = sq / fmaxf(acc, 1e-12f);
#pragma unroll
    for (int off = 32; off > 0; off >>= 1) val += __shfl_xor(val, off, 64);
    if (d == 0) op[i] = tv * val;
  }
}

// softmax over heads; writes fp32 alpha straight into d_out's alpha region
__global__ void softmax_heads(const float* __restrict__ tssa, const float* __restrict__ penalty,
                              const float* __restrict__ gamma, float* __restrict__ alpha_f) {
  const int idx = blockIdx.x * blockDim.x + threadIdx.x;  // over B*T
  const int b = idx >> 12;     // T = 4096
  const int t = idx & 4095;
  const float pen = penalty[idx];
  float sc[NHh];
  float mx = -1e30f;
#pragma unroll
  for (int h = 0; h < NHh; h++) {
    const float s = tssa[((size_t)(b * NHh + h)) * Tt + t] - gamma[h] * pen;
    sc[h] = s;
    mx = fmaxf(mx, s);
  }
  float sum = 0.f;
#pragma unroll
  for (int h = 0; h < NHh; h++) { const float e = expf(sc[h] - mx); sc[h] = e; sum += e; }
  const float inv = 1.f / sum;
#pragma unroll
  for (int h = 0; h < NHh; h++) {
    alpha_f[((size_t)(b * NHh + h)) * Tt + t] = sc[h] * inv;
  }
}

// chunk sums of w_sq*alpha (vec) and alpha (scalar)
__global__ void dots_phase1(const bf16* __restrict__ w, const float* __restrict__ alpha_f,
                            float* __restrict__ S2, float* __restrict__ SA) {
  const int c = blockIdx.x, h = blockIdx.y, b = blockIdx.z, d = threadIdx.x;
  const bf16* wp = w + ((size_t)(b * Tt + c * CHL)) * Dm + h * HD + d;
  const float* ap = alpha_f + (size_t)(b * NHh + h) * Tt + c * CHL;
  float acc = 0.f, acca = 0.f;
  for (int i = 0; i < CHL; i++) {
    const float a = ap[i];
    const float v = bf2f(wp[(size_t)i * Dm]);
    acc += v * v * a;
    acca += a;
  }
  S2[(((size_t)(b * NHh + h) * NCH) + c) * HD + d] = acc;
  if (d == 0) SA[(size_t)(b * NHh + h) * NCH + c] = acca;
}

// y'[b,t,h*64+d] = -w * alpha * min(1/(1+dots), 1e4), bf16
__global__ void y_phase3(const bf16* __restrict__ w, const float* __restrict__ alpha_f,
                         const float* __restrict__ S2ex, const float* __restrict__ SAex,
                         bf16* __restrict__ yprime) {
  const int c = blockIdx.x, h = blockIdx.y, b = blockIdx.z, d = threadIdx.x;
  float accd = S2ex[(((size_t)(b * NHh + h) * NCH) + c) * HD + d];
  float acca = SAex[(size_t)(b * NHh + h) * NCH + c];
  const bf16* wp = w + ((size_t)(b * Tt + c * CHL)) * Dm + h * HD + d;
  const float* ap = alpha_f + (size_t)(b * NHh + h) * Tt + c * CHL;
  bf16* yp = yprime + ((size_t)(b * Tt + c * CHL)) * Dm + h * HD + d;
  for (int i = 0; i < CHL; i++) {
    const float a = ap[i];
    const float v = bf2f(wp[(size_t)i * Dm]);
    const float sq = v * v;
    accd += sq * a;
    acca += a;
    const float dots = accd / (acca + 1e-8f);
    const float attn = fminf(1.f / (1.f + dots), 10000.f);
    yp[(size_t)i * Dm] = __float2bfloat16(-v * a * attn);
  }
}

extern "C" void kernel_launch(void* const* d_in, const int* in_sizes, int n_in,
                              void* d_out, int out_size, void* d_ws, size_t ws_size,
                              hipStream_t stream) {
  // Reference dtypes: ALL inputs float32, outputs (y, alpha) float32.
  const float* x     = (const float*)d_in[0];
  const float* phi   = (const float*)d_in[1];
  const float* Wattn = (const float*)d_in[2];
  const float* Wproj = (const float*)d_in[3];
  const float* gamma = (const float*)d_in[4];
  const float* temp  = (const float*)d_in[5];

  float* y_out    = (float*)d_out;                          // (B,T,D) fp32
  float* alpha_f  = y_out + (size_t)Bb * Tt * Dm;           // (B,NH,T) fp32

  char* ws = (char*)d_ws;
  bf16*  x_bf   = (bf16*)ws;  ws += (size_t)Bb * Tt * Dm * 2;         // 32 MB
  bf16*  Wa_bf  = (bf16*)ws;  ws += (size_t)Dm * Dm * 2;              // 2 MB
  bf16*  Wp_bf  = (bf16*)ws;  ws += (size_t)Dm * Dm * 2;              // 2 MB
  bf16*  w_bf   = (bf16*)ws;  ws += (size_t)Bb * Tt * Dm * 2;         // 32 MB
  float* tssa   = (float*)ws; ws += (size_t)Bb * NHh * Tt * 4;        // 1 MB
  float* pen    = (float*)ws; ws += (size_t)Bb * Tt * 4;              // 64 KB
  float* S1     = (float*)ws; ws += (size_t)Bb * NHh * NCH * HD * 4;  // 1 MB
  float* S2     = (float*)ws; ws += (size_t)Bb * NHh * NCH * HD * 4;  // 1 MB
  float* SA     = (float*)ws; ws += (size_t)Bb * NHh * NCH * 4;       // 16 KB
  bf16*  yprime = x_bf;  // alias: x_bf is dead after GEMM1

  const int M = Bb * Tt, N = Dm, K = Dm;
  dim3 gg(N / 128, M / 128), gb(256);
  dim3 g3(NCH, NHh, Bb), b64(64);

  cast_f32_to_bf16<<<dim3(1024), dim3(256), 0, stream>>>(x, x_bf, Bb * Tt * Dm);
  cast_f32_to_bf16<<<dim3(256), dim3(256), 0, stream>>>(Wattn, Wa_bf, Dm * Dm);
  cast_f32_to_bf16<<<dim3(256), dim3(256), 0, stream>>>(Wproj, Wp_bf, Dm * Dm);

  gemm_bt<true, true><<<gg, gb, 0, stream>>>(x_bf, Wa_bf, (void*)w_bf, S1, M, N, K);
  phi_penalty_kernel<<<dim3(Bb), dim3(256), 0, stream>>>(phi, pen);
  prefix_vec<<<dim3(Bb * NHh), b64, 0, stream>>>(S1);
  tssa_phase3<<<g3, b64, 0, stream>>>(w_bf, S1, temp, tssa);
  softmax_heads<<<dim3(Bb * Tt / 256), dim3(256), 0, stream>>>(tssa, pen, gamma, alpha_f);
  dots_phase1<<<g3, b64, 0, stream>>>(w_bf, alpha_f, S2, SA);
  prefix_dots<<<dim3(Bb * NHh), b64, 0, stream>>>(S2, SA);
  y_phase3<<<g3, b64, 0, stream>>>(w_bf, alpha_f, S2, SA, yprime);
  gemm_bt<false, false><<<gg, gb, 0, stream>>>(yprime, Wp_bf, (void*)y_out, nullptr, M, N, K);
}